// Round 9
// baseline (91.372 us; speedup 1.0000x reference)
//
#include <hip/hip_runtime.h>

typedef __attribute__((ext_vector_type(8))) short short8;
typedef __attribute__((ext_vector_type(4))) float f32x4;
typedef __attribute__((ext_vector_type(8))) unsigned short ushort8;

__device__ __forceinline__ unsigned short f2bf(float x) {
  union { float f; unsigned u; } v; v.f = x;
  unsigned r = v.u + 0x7fffu + ((v.u >> 16) & 1u);   // round-to-nearest-even
  return (unsigned short)(r >> 16);
}

// ---------------- W[h][g] -> Wt[g][h] transpose + convert (512x512) ----------
__global__ __launch_bounds__(256) void wt_kernel(
    const float* __restrict__ W, unsigned short* __restrict__ Wt) {
  __shared__ float s[64][65];
  int g0 = blockIdx.x * 64, h0 = blockIdx.y * 64;
  int tx = threadIdx.x & 63, ty = threadIdx.x >> 6;
#pragma unroll
  for (int rr = 0; rr < 16; ++rr) {
    int h = ty * 16 + rr;
    s[h][tx] = W[(long)(h0 + h) * 512 + g0 + tx];
  }
  __syncthreads();
#pragma unroll
  for (int rr = 0; rr < 16; ++rr) {
    int g = ty * 16 + rr;
    Wt[(long)(g0 + g) * 512 + h0 + tx] = f2bf(s[tx][g]);
  }
}

// ---- Fused: gemm1 (blocks 0..511) + dec fp32->bf16 convert (blocks 512..4607)
__global__ __launch_bounds__(256) void gemm1_plus_cvtdec(
    const float* __restrict__ enc, const unsigned short* __restrict__ Wt,
    unsigned short* __restrict__ encW,
    const float* __restrict__ dec, unsigned short* __restrict__ dec_bf) {
  if (blockIdx.x >= 512) {
    int i = (blockIdx.x - 512) * 256 + threadIdx.x;
    const float4* p = (const float4*)(dec + (long)i * 8);
    float4 a = p[0], b = p[1];
    ushort8 o;
    o[0] = f2bf(a.x); o[1] = f2bf(a.y); o[2] = f2bf(a.z); o[3] = f2bf(a.w);
    o[4] = f2bf(b.x); o[5] = f2bf(b.y); o[6] = f2bf(b.z); o[7] = f2bf(b.w);
    *(ushort8*)(dec_bf + (long)i * 8) = o;
    return;
  }

  constexpr int K = 512, N = 512, BK = 32;
  __shared__ __align__(16) short As[128 * BK];
  __shared__ __align__(16) short Bs[128 * BK];

  const int g = blockIdx.x;
  const int work = (g & 7) * 64 + (g >> 3);      // bijective on [0,512)
  const int bxm = work >> 2, byn = work & 3;

  const int tid = threadIdx.x;
  const int wave = tid >> 6, lane = tid & 63;
  const int wm = wave >> 1, wn = wave & 1;
  const int r = lane & 15, q = lane >> 4;

  const float* Ab = enc + (long)bxm * 128 * K;
  const unsigned short* Bb = Wt + (long)byn * 128 * K;

  const int srow = tid >> 1, shalf = tid & 1;
  const float* arow = Ab + (long)srow * K + shalf * 16;

  f32x4 acc[4][4] = {};
  float4 av[4];
#pragma unroll
  for (int j = 0; j < 4; ++j) av[j] = ((const float4*)arow)[j];

  for (int kt = 0; kt < K; kt += BK) {
    ushort8 o0, o1;
    o0[0] = f2bf(av[0].x); o0[1] = f2bf(av[0].y); o0[2] = f2bf(av[0].z); o0[3] = f2bf(av[0].w);
    o0[4] = f2bf(av[1].x); o0[5] = f2bf(av[1].y); o0[6] = f2bf(av[1].z); o0[7] = f2bf(av[1].w);
    o1[0] = f2bf(av[2].x); o1[1] = f2bf(av[2].y); o1[2] = f2bf(av[2].z); o1[3] = f2bf(av[2].w);
    o1[4] = f2bf(av[3].x); o1[5] = f2bf(av[3].y); o1[6] = f2bf(av[3].z); o1[7] = f2bf(av[3].w);
    *(ushort8*)&As[srow * BK + shalf * 16 + 0] = o0;
    *(ushort8*)&As[srow * BK + shalf * 16 + 8] = o1;

#pragma unroll
    for (int j = 0; j < 2; ++j) {
      int c = (j * 4 + wave) * 64 + lane;
      int row = c >> 2;
      int coff = (c & 3) * 8;
      __builtin_amdgcn_global_load_lds(
          (const __attribute__((address_space(1))) void*)(Bb + (long)row * K + kt + coff),
          (__attribute__((address_space(3))) void*)(Bs + (j * 4 + wave) * 512),
          16, 0, 0);
    }
    __syncthreads();

    short8 af[4], bfr[4];
#pragma unroll
    for (int m = 0; m < 4; ++m)
      af[m] = *(const short8*)&As[(wm * 64 + m * 16 + r) * BK + q * 8];
#pragma unroll
    for (int n = 0; n < 4; ++n)
      bfr[n] = *(const short8*)&Bs[(wn * 64 + n * 16 + r) * BK + q * 8];

    if (kt + BK < K) {
      const float* ap = arow + kt + BK;
#pragma unroll
      for (int j = 0; j < 4; ++j) av[j] = ((const float4*)ap)[j];
    }

#pragma unroll
    for (int m = 0; m < 4; ++m)
#pragma unroll
      for (int n = 0; n < 4; ++n)
        acc[m][n] = __builtin_amdgcn_mfma_f32_16x16x32_bf16(af[m], bfr[n], acc[m][n], 0, 0, 0);
    __syncthreads();
  }

  const long rowbase = (long)bxm * 128 + wm * 64;
  const long colbase = (long)byn * 128 + wn * 64;
#pragma unroll
  for (int m = 0; m < 4; ++m)
#pragma unroll
    for (int n = 0; n < 4; ++n)
#pragma unroll
      for (int j = 0; j < 4; ++j) {
        long row = rowbase + m * 16 + q * 4 + j;
        long col = colbase + n * 16 + r;
        encW[row * (long)N + col] = f2bf(acc[m][n][j]);
      }
}

// ---------------- GEMM2: persistent A-resident strips (race-fixed) ----------
// 256 blocks (1/CU), 512 thr. Block = (batch z = blk&7 -> XCD-pinned, strip).
// A-strip 64x512 bf16 (64KB) loaded ONCE into LDS (XOR-swizzled).
// Flat 128-step pipeline, B-tile 256x32 (16KB) QUAD-buffered, staged 2 ahead.
// Per-step invariant: BSTG(s+2) -> VMCNT(own s-loads retired) -> BARRIER ->
// reads buf s&3. RAW: all waves retired own step-s loads before barrier s.
// WAR: buf (s+2)&3 last read at step s-2 (completes before barrier s-1);
// rewrite issued after barrier s-1. Stores: epilogue in ks=0 read window;
// VMCNT(36) at ks=1,2 skips the 32 queued C-stores (in-order retire).

#define VMCNT(n) asm volatile("s_waitcnt vmcnt(" #n ")" ::: "memory")
#define LGKM0 asm volatile("s_waitcnt lgkmcnt(0)" ::: "memory")
#define BARRIER __builtin_amdgcn_s_barrier()

#define BSTG(LB, S2)                                                          \
  do {                                                                        \
    int nt2_ = (S2) >> 4, ks2_ = (S2) & 15;                                   \
    _Pragma("unroll") for (int j_ = 0; j_ < 2; ++j_) {                        \
      int c_ = w * 2 + j_;                                                    \
      __builtin_amdgcn_global_load_lds(                                       \
          (const __attribute__((address_space(1))) void*)(                    \
              Bb + ((long)(nt2_ * 256 + c_ * 16 + srow)) * 512 + ks2_ * 32 + scol), \
          (__attribute__((address_space(3))) void*)((LB) + (c_ << 10)),       \
          16, 0, 0);                                                          \
    }                                                                         \
  } while (0)

#define FRAGS_MFMA(BUFI, KS)                                                  \
  do {                                                                        \
    const char* Bc_ = BLds + (BUFI) * 16384;                                  \
    _Pragma("unroll") for (int n_ = 0; n_ < 4; ++n_)                          \
      bf[n_] = *(const short8*)(Bc_ + ((wn * 4 + n_) << 10) + lconst);        \
    _Pragma("unroll") for (int i_ = 0; i_ < 2; ++i_) {                        \
      int row_ = wm * 32 + i_ * 16 + base_r;                                  \
      af[i_] = *(const short8*)(ALds + row_ * 1024 +                          \
                                (((KS) * 64 + q * 16) ^ ((row_ & 7) << 4)));  \
    }                                                                         \
    LGKM0;                                                                    \
    __builtin_amdgcn_sched_barrier(0);                                        \
    __builtin_amdgcn_s_setprio(1);                                            \
    _Pragma("unroll") for (int i_ = 0; i_ < 2; ++i_)                          \
      _Pragma("unroll") for (int n_ = 0; n_ < 4; ++n_)                        \
        acc[i_][n_] = __builtin_amdgcn_mfma_f32_16x16x32_bf16(                \
            af[i_], bf[n_], acc[i_][n_], 0, 0, 0);                            \
    __builtin_amdgcn_s_setprio(0);                                            \
  } while (0)

#define EPILOGUE(NT)                                                          \
  do {                                                                        \
    float* Cb_ = C + ((long)z * 2048 + strip * 64 + wm * 32) * 2048 +         \
                 (NT) * 256 + wn * 64;                                        \
    _Pragma("unroll") for (int m_ = 0; m_ < 2; ++m_)                          \
      _Pragma("unroll") for (int n_ = 0; n_ < 4; ++n_)                        \
        _Pragma("unroll") for (int j_ = 0; j_ < 4; ++j_)                      \
          Cb_[(long)(m_ * 16 + q * 4 + j_) * 2048 + n_ * 16 + base_r] =       \
              acc[m_][n_][j_] + bv;                                           \
    _Pragma("unroll") for (int m_ = 0; m_ < 2; ++m_)                          \
      _Pragma("unroll") for (int n_ = 0; n_ < 4; ++n_)                        \
        acc[m_][n_] = (f32x4){0.f, 0.f, 0.f, 0.f};                            \
  } while (0)

__global__ __launch_bounds__(512, 1) void gemm2_persist(
    const unsigned short* __restrict__ A,   // dec_bf [8*2048][512]
    const unsigned short* __restrict__ Bt,  // encW   [8*2048][512]
    float* __restrict__ C, const float* __restrict__ bias) {
  __shared__ __align__(16) char Lds[131072];   // A 64KB + B 4x16KB

  const int blk = blockIdx.x;
  const int z = blk & 7, strip = blk >> 3;     // batch -> XCD pinning
  const int tid = threadIdx.x;
  const int w = tid >> 6, lane = tid & 63;
  const int wm = w >> 2, wn = w & 3;           // 2x4 waves: 32x64 out each
  const int base_r = lane & 15, q = lane >> 4;
  const int lconst = base_r * 64 + ((q * 16) ^ ((base_r & 8) << 2));
  const int srow = lane >> 2;
  const int scol = ((lane & 3) * 8) ^ (((lane >> 5) & 1) << 4);

  const unsigned short* Arow0 = A + ((long)z * 2048 + strip * 64) * 512;
  const unsigned short* Bb = Bt + (long)z * 2048 * 512;
  char* ALds = Lds;
  char* BLds = Lds + 65536;

  f32x4 acc[2][4] = {};
  short8 af[2];
  short8 bf[4];

  // ---- prologue: A -> regs (coalesced), stage B steps 0,1; A -> LDS swizzled
  ushort8 areg[8];
  const int arw = tid >> 6, acolb = (tid & 63) * 16;
#pragma unroll
  for (int i = 0; i < 8; ++i)
    areg[i] = *(const ushort8*)((const char*)Arow0 + (long)(i * 8 + arw) * 1024 + acolb);
  BSTG(BLds + 0 * 16384, 0);
  BSTG(BLds + 1 * 16384, 1);
  VMCNT(4);                       // A regs retired (B0,B1 in flight)
#pragma unroll
  for (int i = 0; i < 8; ++i) {
    int row = i * 8 + arw;
    *(ushort8*)(ALds + row * 1024 + (acolb ^ ((row & 7) << 4))) = areg[i];
  }
  LGKM0;                          // own A ds_writes done before first barrier

  const float bv = bias[0];

  for (int nt = 0; nt < 8; ++nt) {
    const int s0 = nt * 16;
    // ks = 0
    BSTG(BLds + ((s0 + 2) & 3) * 16384, s0 + 2);
    VMCNT(4);                     // retire own step-s0 loads
    BARRIER;
    if (nt > 0) EPILOGUE(nt - 1); // 32 stores enter FIFO after [s0+1][s0+2]
    FRAGS_MFMA(s0 & 3, 0);
    // ks = 1
    BSTG(BLds + ((s0 + 3) & 3) * 16384, s0 + 3);
    if (nt == 0) { VMCNT(4); } else { VMCNT(36); }   // retire s0+1, skip stores
    BARRIER;
    FRAGS_MFMA((s0 + 1) & 3, 1);
    // ks = 2
    BSTG(BLds + ((s0 + 4) & 3) * 16384, s0 + 4);
    if (nt == 0) { VMCNT(4); } else { VMCNT(36); }   // retire s0+2, skip stores
    BARRIER;
    FRAGS_MFMA((s0 + 2) & 3, 2);
    // ks = 3..13 steady state (VMCNT(4) at ks=3 also drains the 32 stores)
    for (int ks = 3; ks <= 13; ++ks) {
      const int s = s0 + ks;
      BSTG(BLds + ((s + 2) & 3) * 16384, s + 2);
      VMCNT(4);
      BARRIER;
      FRAGS_MFMA(s & 3, ks);
    }
    // ks = 14, 15 (last staged step is 127)
    if (nt < 7) {
      BSTG(BLds + ((s0 + 16) & 3) * 16384, s0 + 16);
      VMCNT(4);
    } else {
      VMCNT(2);
    }
    BARRIER;
    FRAGS_MFMA((s0 + 14) & 3, 14);
    if (nt < 7) {
      BSTG(BLds + ((s0 + 17) & 3) * 16384, s0 + 17);
      VMCNT(4);
    } else {
      VMCNT(0);
    }
    BARRIER;
    FRAGS_MFMA((s0 + 15) & 3, 15);
  }
  EPILOGUE(7);
}

extern "C" void kernel_launch(void* const* d_in, const int* in_sizes, int n_in,
                              void* d_out, int out_size, void* d_ws, size_t ws_size,
                              hipStream_t stream) {
  const float* enc  = (const float*)d_in[0];  // [8,2048,512]
  const float* dec  = (const float*)d_in[1];  // [8,2048,512]
  const float* W    = (const float*)d_in[2];  // [1,512,512]
  const float* bias = (const float*)d_in[3];  // [1]
  float* out = (float*)d_out;                 // [8,2048,2048] fp32

  constexpr int Bn = 8, S = 2048, H = 512;
  constexpr long NE = (long)Bn * S * H;       // 8388608

  unsigned short* dec_bf = (unsigned short*)d_ws;        // 16.8 MB
  unsigned short* Wt     = dec_bf + NE;                  // 0.5 MB
  unsigned short* encW   = Wt + (long)H * H;             // 16.8 MB

  wt_kernel<<<dim3(8, 8), 256, 0, stream>>>(W, Wt);

  // gemm1 (512 blocks) + dec conversion (4096 blocks) in one launch
  gemm1_plus_cvtdec<<<dim3(512 + 4096, 1, 1), 256, 0, stream>>>(
      enc, Wt, encW, dec, dec_bf);

  // scores[b][d][e] = dec[b,d,:] . encW[b,e,:] + bias
  gemm2_persist<<<dim3(256, 1, 1), 512, 0, stream>>>(dec_bf, encW, out, bias);
}

// Round 10
// 84.726 us; speedup vs baseline: 1.0784x; 1.0784x over previous
//
#include <hip/hip_runtime.h>

typedef __attribute__((ext_vector_type(8))) short short8;
typedef __attribute__((ext_vector_type(4))) float f32x4;
typedef __attribute__((ext_vector_type(8))) unsigned short ushort8;

__device__ __forceinline__ unsigned short f2bf(float x) {
  union { float f; unsigned u; } v; v.f = x;
  unsigned r = v.u + 0x7fffu + ((v.u >> 16) & 1u);   // round-to-nearest-even
  return (unsigned short)(r >> 16);
}

// ---------------- W[h][g] -> Wt[g][h] transpose + convert (512x512) ----------
__global__ __launch_bounds__(256) void wt_kernel(
    const float* __restrict__ W, unsigned short* __restrict__ Wt) {
  __shared__ float s[64][65];
  int g0 = blockIdx.x * 64, h0 = blockIdx.y * 64;
  int tx = threadIdx.x & 63, ty = threadIdx.x >> 6;
#pragma unroll
  for (int rr = 0; rr < 16; ++rr) {
    int h = ty * 16 + rr;
    s[h][tx] = W[(long)(h0 + h) * 512 + g0 + tx];
  }
  __syncthreads();
#pragma unroll
  for (int rr = 0; rr < 16; ++rr) {
    int g = ty * 16 + rr;
    Wt[(long)(g0 + g) * 512 + h0 + tx] = f2bf(s[tx][g]);
  }
}

// ---- Fused: gemm1 (blocks 0..511) + dec fp32->bf16 convert (blocks 512..4607)
__global__ __launch_bounds__(256) void gemm1_plus_cvtdec(
    const float* __restrict__ enc, const unsigned short* __restrict__ Wt,
    unsigned short* __restrict__ encW,
    const float* __restrict__ dec, unsigned short* __restrict__ dec_bf) {
  if (blockIdx.x >= 512) {
    int i = (blockIdx.x - 512) * 256 + threadIdx.x;
    const float4* p = (const float4*)(dec + (long)i * 8);
    float4 a = p[0], b = p[1];
    ushort8 o;
    o[0] = f2bf(a.x); o[1] = f2bf(a.y); o[2] = f2bf(a.z); o[3] = f2bf(a.w);
    o[4] = f2bf(b.x); o[5] = f2bf(b.y); o[6] = f2bf(b.z); o[7] = f2bf(b.w);
    *(ushort8*)(dec_bf + (long)i * 8) = o;
    return;
  }

  constexpr int K = 512, N = 512, BK = 32;
  __shared__ __align__(16) short As[128 * BK];
  __shared__ __align__(16) short Bs[128 * BK];

  const int g = blockIdx.x;
  const int work = (g & 7) * 64 + (g >> 3);      // bijective on [0,512)
  const int bxm = work >> 2, byn = work & 3;

  const int tid = threadIdx.x;
  const int wave = tid >> 6, lane = tid & 63;
  const int wm = wave >> 1, wn = wave & 1;
  const int r = lane & 15, q = lane >> 4;

  const float* Ab = enc + (long)bxm * 128 * K;
  const unsigned short* Bb = Wt + (long)byn * 128 * K;

  const int srow = tid >> 1, shalf = tid & 1;
  const float* arow = Ab + (long)srow * K + shalf * 16;

  f32x4 acc[4][4] = {};
  float4 av[4];
#pragma unroll
  for (int j = 0; j < 4; ++j) av[j] = ((const float4*)arow)[j];

  for (int kt = 0; kt < K; kt += BK) {
    ushort8 o0, o1;
    o0[0] = f2bf(av[0].x); o0[1] = f2bf(av[0].y); o0[2] = f2bf(av[0].z); o0[3] = f2bf(av[0].w);
    o0[4] = f2bf(av[1].x); o0[5] = f2bf(av[1].y); o0[6] = f2bf(av[1].z); o0[7] = f2bf(av[1].w);
    o1[0] = f2bf(av[2].x); o1[1] = f2bf(av[2].y); o1[2] = f2bf(av[2].z); o1[3] = f2bf(av[2].w);
    o1[4] = f2bf(av[3].x); o1[5] = f2bf(av[3].y); o1[6] = f2bf(av[3].z); o1[7] = f2bf(av[3].w);
    *(ushort8*)&As[srow * BK + shalf * 16 + 0] = o0;
    *(ushort8*)&As[srow * BK + shalf * 16 + 8] = o1;

#pragma unroll
    for (int j = 0; j < 2; ++j) {
      int c = (j * 4 + wave) * 64 + lane;
      int row = c >> 2;
      int coff = (c & 3) * 8;
      __builtin_amdgcn_global_load_lds(
          (const __attribute__((address_space(1))) void*)(Bb + (long)row * K + kt + coff),
          (__attribute__((address_space(3))) void*)(Bs + (j * 4 + wave) * 512),
          16, 0, 0);
    }
    __syncthreads();

    short8 af[4], bfr[4];
#pragma unroll
    for (int m = 0; m < 4; ++m)
      af[m] = *(const short8*)&As[(wm * 64 + m * 16 + r) * BK + q * 8];
#pragma unroll
    for (int n = 0; n < 4; ++n)
      bfr[n] = *(const short8*)&Bs[(wn * 64 + n * 16 + r) * BK + q * 8];

    if (kt + BK < K) {
      const float* ap = arow + kt + BK;
#pragma unroll
      for (int j = 0; j < 4; ++j) av[j] = ((const float4*)ap)[j];
    }

#pragma unroll
    for (int m = 0; m < 4; ++m)
#pragma unroll
      for (int n = 0; n < 4; ++n)
        acc[m][n] = __builtin_amdgcn_mfma_f32_16x16x32_bf16(af[m], bfr[n], acc[m][n], 0, 0, 0);
    __syncthreads();
  }

  const long rowbase = (long)bxm * 128 + wm * 64;
  const long colbase = (long)byn * 128 + wn * 64;
#pragma unroll
  for (int m = 0; m < 4; ++m)
#pragma unroll
    for (int n = 0; n < 4; ++n)
#pragma unroll
      for (int j = 0; j < 4; ++j) {
        long row = rowbase + m * 16 + q * 4 + j;
        long col = colbase + n * 16 + r;
        encW[row * (long)N + col] = f2bf(acc[m][n][j]);
      }
}

// ---------------- GEMM2: m97-style 2-barrier loop, 128(M)x256(N), BK=32 ------
// scores[b][d][e] = sum_g dec_bf[b,d,g] * encW[b,e,g] + bias
// 256 thr, 4 waves (2x2) of 64x128 out: 32 MFMA + 12 swizzled ds_read_b128 per
// wave per barrier window (2x the m97-128^2 ratio). LDS 24KB single-buffered,
// swizzled 1024B chunks (16 rows x 32 k, bank-conflict-free reads — verified
// R5 SQ_LDS_BANK_CONFLICT=0). acc ~196 VGPR -> __launch_bounds__(256,2):
// 2 blocks/CU co-resident cover each other's barrier drains (R6-proven).
__global__ __launch_bounds__(256, 2) void gemm2_w256(
    const unsigned short* __restrict__ A,   // dec_bf [8*2048][512]
    const unsigned short* __restrict__ Bt,  // encW   [8*2048][512]
    float* __restrict__ C, const float* __restrict__ bias) {
  constexpr int K = 512;
  __shared__ __align__(16) char As[8192];    // 8 chunks  (128 rows x 32 k)
  __shared__ __align__(16) char Bs[16384];   // 16 chunks (256 rows x 32 k)

  // grid 1024 = 8 batches x (16 m-tiles x 8 n-tiles); z = blk&7 pins batch->XCD
  const int flat = blockIdx.x;
  const int z = flat & 7;
  const int work = flat >> 3;
  const int by = work & 7, bx = work >> 3;   // consecutive work: same A-panel

  const int tid = threadIdx.x;
  const int wave = tid >> 6, lane = tid & 63;
  const int wm = wave >> 1, wn = wave & 1;   // 2x2 waves: 64(M) x 128(N) each
  const int base_r = lane & 15, q = lane >> 4;
  const int lconst = base_r * 64 + ((q * 16) ^ ((base_r & 8) << 2));
  const int srow = lane >> 2;
  const int scol = ((lane & 3) * 8) ^ (((lane >> 5) & 1) << 4);

  const unsigned short* Ab = A + ((long)z * 2048 + bx * 128) * 512;
  const unsigned short* Bb = Bt + ((long)z * 2048 + by * 256) * 512;

  f32x4 acc[4][8] = {};

  for (int kt = 0; kt < K; kt += 32) {
    // stage 24 chunks (A:8, B:16), 6 per wave, pre-swizzled source + linear dest
#pragma unroll
    for (int j = 0; j < 6; ++j) {
      int c = wave * 6 + j;
      if (c < 8) {
        __builtin_amdgcn_global_load_lds(
            (const __attribute__((address_space(1))) void*)(
                Ab + (long)(c * 16 + srow) * 512 + kt + scol),
            (__attribute__((address_space(3))) void*)(As + (c << 10)),
            16, 0, 0);
      } else {
        int cb = c - 8;
        __builtin_amdgcn_global_load_lds(
            (const __attribute__((address_space(1))) void*)(
                Bb + (long)(cb * 16 + srow) * 512 + kt + scol),
            (__attribute__((address_space(3))) void*)(Bs + (cb << 10)),
            16, 0, 0);
      }
    }
    __syncthreads();

    short8 af[4], bfr[8];
#pragma unroll
    for (int m = 0; m < 4; ++m)
      af[m] = *(const short8*)(As + ((wm * 4 + m) << 10) + lconst);
#pragma unroll
    for (int n = 0; n < 8; ++n)
      bfr[n] = *(const short8*)(Bs + ((wn * 8 + n) << 10) + lconst);

#pragma unroll
    for (int m = 0; m < 4; ++m)
#pragma unroll
      for (int n = 0; n < 8; ++n)
        acc[m][n] = __builtin_amdgcn_mfma_f32_16x16x32_bf16(af[m], bfr[n], acc[m][n], 0, 0, 0);
    __syncthreads();
  }

  const float bv = bias[0];
  float* Cb = C + ((long)z * 2048 + bx * 128 + wm * 64) * 2048 + by * 256 + wn * 128;
#pragma unroll
  for (int m = 0; m < 4; ++m)
#pragma unroll
    for (int n = 0; n < 8; ++n)
#pragma unroll
      for (int j = 0; j < 4; ++j)
        Cb[(long)(m * 16 + q * 4 + j) * 2048 + n * 16 + base_r] = acc[m][n][j] + bv;
}

extern "C" void kernel_launch(void* const* d_in, const int* in_sizes, int n_in,
                              void* d_out, int out_size, void* d_ws, size_t ws_size,
                              hipStream_t stream) {
  const float* enc  = (const float*)d_in[0];  // [8,2048,512]
  const float* dec  = (const float*)d_in[1];  // [8,2048,512]
  const float* W    = (const float*)d_in[2];  // [1,512,512]
  const float* bias = (const float*)d_in[3];  // [1]
  float* out = (float*)d_out;                 // [8,2048,2048] fp32

  constexpr int Bn = 8, S = 2048, H = 512;
  constexpr long NE = (long)Bn * S * H;       // 8388608

  unsigned short* dec_bf = (unsigned short*)d_ws;        // 16.8 MB
  unsigned short* Wt     = dec_bf + NE;                  // 0.5 MB
  unsigned short* encW   = Wt + (long)H * H;             // 16.8 MB

  wt_kernel<<<dim3(8, 8), 256, 0, stream>>>(W, Wt);

  // gemm1 (512 blocks) + dec conversion (4096 blocks) in one launch
  gemm1_plus_cvtdec<<<dim3(512 + 4096, 1, 1), 256, 0, stream>>>(
      enc, Wt, encW, dec, dec_bf);

  // scores[b][d][e] = dec[b,d,:] . encW[b,e,:] + bias
  gemm2_w256<<<dim3(1024, 1, 1), 256, 0, stream>>>(dec_bf, encW, out, bias);
}

// Round 11
// 81.832 us; speedup vs baseline: 1.1166x; 1.0354x over previous
//
#include <hip/hip_runtime.h>

typedef __attribute__((ext_vector_type(8))) short short8;
typedef __attribute__((ext_vector_type(4))) float f32x4;
typedef __attribute__((ext_vector_type(8))) unsigned short ushort8;

__device__ __forceinline__ unsigned short f2bf(float x) {
  union { float f; unsigned u; } v; v.f = x;
  unsigned r = v.u + 0x7fffu + ((v.u >> 16) & 1u);   // round-to-nearest-even
  return (unsigned short)(r >> 16);
}

// ---------------- W[h][g] -> Wt[g][h] transpose + convert (512x512) ----------
__global__ __launch_bounds__(256) void wt_kernel(
    const float* __restrict__ W, unsigned short* __restrict__ Wt) {
  __shared__ float s[64][65];
  int g0 = blockIdx.x * 64, h0 = blockIdx.y * 64;
  int tx = threadIdx.x & 63, ty = threadIdx.x >> 6;
#pragma unroll
  for (int rr = 0; rr < 16; ++rr) {
    int h = ty * 16 + rr;
    s[h][tx] = W[(long)(h0 + h) * 512 + g0 + tx];
  }
  __syncthreads();
#pragma unroll
  for (int rr = 0; rr < 16; ++rr) {
    int g = ty * 16 + rr;
    Wt[(long)(g0 + g) * 512 + h0 + tx] = f2bf(s[tx][g]);
  }
}

// ---- Fused: gemm1 (blocks 0..511) + dec fp32->bf16 convert (blocks 512..4607)
__global__ __launch_bounds__(256) void gemm1_plus_cvtdec(
    const float* __restrict__ enc, const unsigned short* __restrict__ Wt,
    unsigned short* __restrict__ encW,
    const float* __restrict__ dec, unsigned short* __restrict__ dec_bf) {
  if (blockIdx.x >= 512) {
    int i = (blockIdx.x - 512) * 256 + threadIdx.x;
    const float4* p = (const float4*)(dec + (long)i * 8);
    float4 a = p[0], b = p[1];
    ushort8 o;
    o[0] = f2bf(a.x); o[1] = f2bf(a.y); o[2] = f2bf(a.z); o[3] = f2bf(a.w);
    o[4] = f2bf(b.x); o[5] = f2bf(b.y); o[6] = f2bf(b.z); o[7] = f2bf(b.w);
    *(ushort8*)(dec_bf + (long)i * 8) = o;
    return;
  }

  constexpr int K = 512, N = 512, BK = 32;
  __shared__ __align__(16) short As[128 * BK];
  __shared__ __align__(16) short Bs[128 * BK];

  const int g = blockIdx.x;
  const int work = (g & 7) * 64 + (g >> 3);      // bijective on [0,512)
  const int bxm = work >> 2, byn = work & 3;

  const int tid = threadIdx.x;
  const int wave = tid >> 6, lane = tid & 63;
  const int wm = wave >> 1, wn = wave & 1;
  const int r = lane & 15, q = lane >> 4;

  const float* Ab = enc + (long)bxm * 128 * K;
  const unsigned short* Bb = Wt + (long)byn * 128 * K;

  const int srow = tid >> 1, shalf = tid & 1;
  const float* arow = Ab + (long)srow * K + shalf * 16;

  f32x4 acc[4][4] = {};
  float4 av[4];
#pragma unroll
  for (int j = 0; j < 4; ++j) av[j] = ((const float4*)arow)[j];

  for (int kt = 0; kt < K; kt += BK) {
    ushort8 o0, o1;
    o0[0] = f2bf(av[0].x); o0[1] = f2bf(av[0].y); o0[2] = f2bf(av[0].z); o0[3] = f2bf(av[0].w);
    o0[4] = f2bf(av[1].x); o0[5] = f2bf(av[1].y); o0[6] = f2bf(av[1].z); o0[7] = f2bf(av[1].w);
    o1[0] = f2bf(av[2].x); o1[1] = f2bf(av[2].y); o1[2] = f2bf(av[2].z); o1[3] = f2bf(av[2].w);
    o1[4] = f2bf(av[3].x); o1[5] = f2bf(av[3].y); o1[6] = f2bf(av[3].z); o1[7] = f2bf(av[3].w);
    *(ushort8*)&As[srow * BK + shalf * 16 + 0] = o0;
    *(ushort8*)&As[srow * BK + shalf * 16 + 8] = o1;

#pragma unroll
    for (int j = 0; j < 2; ++j) {
      int c = (j * 4 + wave) * 64 + lane;
      int row = c >> 2;
      int coff = (c & 3) * 8;
      __builtin_amdgcn_global_load_lds(
          (const __attribute__((address_space(1))) void*)(Bb + (long)row * K + kt + coff),
          (__attribute__((address_space(3))) void*)(Bs + (j * 4 + wave) * 512),
          16, 0, 0);
    }
    __syncthreads();

    short8 af[4], bfr[4];
#pragma unroll
    for (int m = 0; m < 4; ++m)
      af[m] = *(const short8*)&As[(wm * 64 + m * 16 + r) * BK + q * 8];
#pragma unroll
    for (int n = 0; n < 4; ++n)
      bfr[n] = *(const short8*)&Bs[(wn * 64 + n * 16 + r) * BK + q * 8];

    if (kt + BK < K) {
      const float* ap = arow + kt + BK;
#pragma unroll
      for (int j = 0; j < 4; ++j) av[j] = ((const float4*)ap)[j];
    }

#pragma unroll
    for (int m = 0; m < 4; ++m)
#pragma unroll
      for (int n = 0; n < 4; ++n)
        acc[m][n] = __builtin_amdgcn_mfma_f32_16x16x32_bf16(af[m], bfr[n], acc[m][n], 0, 0, 0);
    __syncthreads();
  }

  const long rowbase = (long)bxm * 128 + wm * 64;
  const long colbase = (long)byn * 128 + wn * 64;
#pragma unroll
  for (int m = 0; m < 4; ++m)
#pragma unroll
    for (int n = 0; n < 4; ++n)
#pragma unroll
      for (int j = 0; j < 4; ++j) {
        long row = rowbase + m * 16 + q * 4 + j;
        long col = colbase + n * 16 + r;
        encW[row * (long)N + col] = f2bf(acc[m][n][j]);
      }
}

// ---------------- GEMM2: 128x128, BK=128, single-buffered, 2 blocks/CU -------
// scores[b][d][e] = sum_g dec_bf[b,d,g] * encW[b,e,g] + bias
// 4 fat K-windows (vs 16 thin): per window stage 64KB (16 gload_lds/thread),
// one sync, then 64 MFMA/wave (4 kk-slices x 16). Sync events per block: 8
// (vs 32 in R6) -> 4x less barrier-drain overhead. Two co-resident blocks
// anti-phase: one stages while the other computes (m114 overlap).
// Chunk layout: 1KB = 16 rows x 32 k, c = rowchunk*4 + kk; same verified
// swizzle (R5: SQ_LDS_BANK_CONFLICT = 0) and C/D epilogue mapping.
__global__ __launch_bounds__(256, 2) void gemm2_bk128(
    const unsigned short* __restrict__ A,   // dec_bf [8*2048][512]
    const unsigned short* __restrict__ Bt,  // encW   [8*2048][512]
    float* __restrict__ C, const float* __restrict__ bias) {
  __shared__ __align__(16) char As[32768];   // 128 rows x 128 k bf16
  __shared__ __align__(16) char Bs[32768];

  // grid 2048 = 8 batches x 16x16 tiles; z = blk&7 pins batch -> XCD (4MB L2)
  const int flat = blockIdx.x;
  const int z = flat & 7;
  const int work = flat >> 3;
  const int by = work & 15, bx = work >> 4;

  const int tid = threadIdx.x;
  const int w = tid >> 6, lane = tid & 63;
  const int wm = w >> 1, wn = w & 1;         // 2x2 waves, 64x64 out each
  const int base_r = lane & 15, q = lane >> 4;
  const int lconst = base_r * 64 + ((q * 16) ^ ((base_r & 8) << 2));
  const int srow = lane >> 2;
  const int scol = ((lane & 3) * 8) ^ (((lane >> 5) & 1) << 4);

  const unsigned short* Ab = A + ((long)z * 2048 + bx * 128) * 512;
  const unsigned short* Bb = Bt + ((long)z * 2048 + by * 128) * 512;

  f32x4 acc[4][4] = {};

  for (int kt = 0; kt < 4; ++kt) {
    // stage 64KB: 32 A-chunks + 32 B-chunks, 8+8 wave-instrs per wave
#pragma unroll
    for (int j = 0; j < 8; ++j) {
      int c = w * 8 + j;                     // chunk 0..31
      int rowc = c >> 2, kk = c & 3;
      __builtin_amdgcn_global_load_lds(
          (const __attribute__((address_space(1))) void*)(
              Ab + (long)(rowc * 16 + srow) * 512 + kt * 128 + kk * 32 + scol),
          (__attribute__((address_space(3))) void*)(As + (c << 10)),
          16, 0, 0);
      __builtin_amdgcn_global_load_lds(
          (const __attribute__((address_space(1))) void*)(
              Bb + (long)(rowc * 16 + srow) * 512 + kt * 128 + kk * 32 + scol),
          (__attribute__((address_space(3))) void*)(Bs + (c << 10)),
          16, 0, 0);
    }
    __syncthreads();

#pragma unroll
    for (int kk = 0; kk < 4; ++kk) {
      short8 af[4], bfr[4];
#pragma unroll
      for (int m = 0; m < 4; ++m)
        af[m] = *(const short8*)(As + (((wm * 4 + m) * 4 + kk) << 10) + lconst);
#pragma unroll
      for (int n = 0; n < 4; ++n)
        bfr[n] = *(const short8*)(Bs + (((wn * 4 + n) * 4 + kk) << 10) + lconst);
#pragma unroll
      for (int m = 0; m < 4; ++m)
#pragma unroll
        for (int n = 0; n < 4; ++n)
          acc[m][n] = __builtin_amdgcn_mfma_f32_16x16x32_bf16(af[m], bfr[n], acc[m][n], 0, 0, 0);
    }
    __syncthreads();
  }

  const float bv = bias[0];
  float* Cb = C + ((long)z * 2048 + bx * 128 + wm * 64) * 2048 + by * 128 + wn * 64;
#pragma unroll
  for (int m = 0; m < 4; ++m)
#pragma unroll
    for (int n = 0; n < 4; ++n)
#pragma unroll
      for (int j = 0; j < 4; ++j)
        Cb[(long)(m * 16 + q * 4 + j) * 2048 + n * 16 + base_r] = acc[m][n][j] + bv;
}

extern "C" void kernel_launch(void* const* d_in, const int* in_sizes, int n_in,
                              void* d_out, int out_size, void* d_ws, size_t ws_size,
                              hipStream_t stream) {
  const float* enc  = (const float*)d_in[0];  // [8,2048,512]
  const float* dec  = (const float*)d_in[1];  // [8,2048,512]
  const float* W    = (const float*)d_in[2];  // [1,512,512]
  const float* bias = (const float*)d_in[3];  // [1]
  float* out = (float*)d_out;                 // [8,2048,2048] fp32

  constexpr int Bn = 8, S = 2048, H = 512;
  constexpr long NE = (long)Bn * S * H;       // 8388608

  unsigned short* dec_bf = (unsigned short*)d_ws;        // 16.8 MB
  unsigned short* Wt     = dec_bf + NE;                  // 0.5 MB
  unsigned short* encW   = Wt + (long)H * H;             // 16.8 MB

  wt_kernel<<<dim3(8, 8), 256, 0, stream>>>(W, Wt);

  // gemm1 (512 blocks) + dec conversion (4096 blocks) in one launch
  gemm1_plus_cvtdec<<<dim3(512 + 4096, 1, 1), 256, 0, stream>>>(
      enc, Wt, encW, dec, dec_bf);

  // scores[b][d][e] = dec[b,d,:] . encW[b,e,:] + bias
  gemm2_bk128<<<dim3(2048, 1, 1), 256, 0, stream>>>(dec_bf, encW, out, bias);
}